// Round 22
// baseline (62.472 us; speedup 1.0000x reference)
//
#include <hip/hip_runtime.h>

#define HH 512
#define WW 512
#define HO 502
#define WO 502
#define KS 11
#define OTH 32                 // v-rows per tile
#define RPT 8                  // v-rows per wave (4 waves)
#define NR  (RPT + KS - 1)     // 18 input rows per thread
#define OTW 48                 // output cols per tile (R17 geometry)
#define VW  58                 // v-cols = OTW + KS - 1
#define CSTR 33                // per-column stride in f32x2 (odd -> uniform-4 banks)
#define CPT 6                  // output cols per thread in phase 2 (8 groups x 6)
#define NPOS (CPT + KS - 1)    // 16 tap positions

#define NTX 11                 // x tiles (11*48 = 528 >= 502)
#define NTY 16                 // y tiles
#define NTILES (NTX * NTY)     // 176
#define NZ 48                  // B*C planes
#define TOTW (NTILES * NZ)     // 8448 tile-slices
#define NBLK 1280              // 5 blocks/CU x 256 CU (R15/R17 proven)
#define WQ (TOTW / NBLK)       // 6
#define WR (TOTW % NBLK)       // 768 blocks take one extra

typedef float f32x2 __attribute__((ext_vector_type(2)));

__device__ __forceinline__ float rfl(float x) {
    union { float f; int i; } u;
    u.f = x;
    u.i = __builtin_amdgcn_readfirstlane(u.i);
    return u.f;
}
__device__ __forceinline__ int rfli(int x) {
    return __builtin_amdgcn_readfirstlane(x);
}

// symmetric gaussian lookup, k compile-time
#define GW(k) g[(k) < 6 ? (k) : 10 - (k)]

__global__ __launch_bounds__(256)
void ssim_sep_kernel(
    const float* __restrict__ img1, const float* __restrict__ img2,
    const float* __restrict__ win, double* __restrict__ acc)
{
    // channel-paired intermediate: chp0 = {mu_s, mu_d}, chp1 = {E[s^2], E[d^2]}
    // Wave w exclusively owns v-rows [8w, 8w+8) -> no cross-wave deps, no barriers.
    __shared__ __align__(16) f32x2 vbuf2[2][VW][CSTR];   // 30,624 B -> 5 blocks/CU
    __shared__ float wsum[4];

    const int tid = threadIdx.x;
    const int bid = blockIdx.x;

    // 1-D gaussian (wave-uniform -> SGPRs): g[k] = w[5][k]/sqrt(w[5][5]); symmetric
    float g[6];
    {
        double inv = 1.0 / sqrt((double)win[5 * KS + 5]);
        #pragma unroll
        for (int k = 0; k < 6; ++k)
            g[k] = rfl((float)((double)win[5 * KS + k] * inv));
    }

    // ---- fixed per-thread roles ----
    const int lane = tid & 63;              // phase-1 v column
    const int wv   = tid >> 6;              // wave id 0..3
    const int j0   = rfli(wv * RPT);        // first v-row owned (wave-uniform SGPR)
    const int rl = lane & 7;                // phase-2: row within wave group
    const int cg = lane >> 3;               // phase-2: col group 0..7 (all active)
    const int c0 = cg * CPT;                // 0,6,...,42 ; max tap col 42+15=57=VW-1
    const int rowl = j0 + rl;               // local v-row for phase 2
    const float c1 = 1e-4f, c2 = 9e-4f;     // L = 1 for [0,1) inputs

    // ---- work chunk: contiguous [w0, w0+cnt) of 8448 tile-slices ----
    int w0, cnt;
    if (bid < WR) { w0 = bid * (WQ + 1);            cnt = WQ + 1; }
    else          { w0 = WR * (WQ + 1) + (bid - WR) * WQ; cnt = WQ; }
    w0 = rfli(w0); cnt = rfli(cnt);

    // issue-cursor state (SGPR), leads processing by up to 2 items
    int z   = rfli(w0 / NTILES);
    int rem = rfli(w0 % NTILES);
    int ty  = rfli(rem / NTX);
    int tx  = rfli(rem % NTX);
    int zoff = rfli(z * (HH * WW));
    int off0 = rfli(zoff + ty * (OTH * WW) + tx * OTW);
    int oy = rfli(ty * OTH), ox = rfli(tx * OTW);

    // depth-2 pipeline buffers (statically named; rule #20)
    float aA[NR], bA[NR], aB[NR], bB[NR];

#define ISSUE_INTO(aX, bX)                                            \
    {                                                                 \
        if (tx == NTX - 1 || ty == NTY - 1) {                         \
            int gc_ = ox + lane; if (gc_ > WW - 1) gc_ = WW - 1;      \
            int r0_ = oy + j0;                                        \
            _Pragma("unroll")                                         \
            for (int ri = 0; ri < NR; ++ri) {                         \
                int gr_ = r0_ + ri; if (gr_ > HH - 1) gr_ = HH - 1;   \
                int ro_ = zoff + gr_ * WW + gc_;                      \
                aX[ri] = img1[ro_];                                   \
                bX[ri] = img2[ro_];                                   \
            }                                                         \
        } else {                                                      \
            const float* pa_ = img1 + off0 + (j0 * WW) + lane;        \
            const float* pb_ = img2 + off0 + (j0 * WW) + lane;        \
            _Pragma("unroll")                                         \
            for (int ri = 0; ri < NR; ++ri) {                         \
                aX[ri] = pa_[ri * WW];                                \
                bX[ri] = pb_[ri * WW];                                \
            }                                                         \
        }                                                             \
    }

#define ADV()                                                         \
    {                                                                 \
        tx = rfli(tx + 1); off0 = rfli(off0 + OTW); ox = rfli(ox + OTW); \
        if (tx == NTX) {                                              \
            tx = 0; ox = 0;                                           \
            off0 = rfli(off0 + (OTH * WW) - (NTX * OTW));             \
            ty = rfli(ty + 1); oy = rfli(oy + OTH);                   \
            if (ty == NTY) {                                          \
                ty = 0; oy = 0;                                       \
                zoff = rfli(zoff + (HH * WW));                        \
                off0 = zoff;                                          \
            }                                                         \
        }                                                             \
    }

    // prologue: fill both pipeline stages
    int oxA = ox, oyA = oy, oxB = ox, oyB = oy;
    ISSUE_INTO(aA, bA); oxA = rfli(ox); oyA = rfli(oy); ADV();
    if (cnt > 1) { ISSUE_INTO(aB, bB); oxB = rfli(ox); oyB = rfli(oy); ADV(); }

    float lsum = 0.f;

    // body for one item from buffer X; issues item i+2 into the same buffer
#define BODY(aX, bX, oxX, oyX, I)                                       \
    {                                                                   \
        /* phase 1 half A: rows j0..j0+3 (inputs 0..13), fold inline */ \
        {                                                               \
            f32x2 mu[4], es[4];                                         \
            _Pragma("unroll")                                           \
            for (int j = 0; j < 4; ++j) {                               \
                mu[j] = (f32x2){0.f, 0.f};                              \
                es[j] = (f32x2){0.f, 0.f};                              \
            }                                                           \
            _Pragma("unroll")                                           \
            for (int ri = 0; ri < 14; ++ri) {                           \
                f32x2 sv = {aX[ri] + bX[ri], aX[ri] - bX[ri]};          \
                f32x2 sq = sv * sv;                                     \
                _Pragma("unroll")                                       \
                for (int j = 0; j < 4; ++j) {                           \
                    int k = ri - j;                                     \
                    if (k >= 0 && k < KS) {                             \
                        float wk = GW(k);                               \
                        mu[j] += wk * sv;                               \
                        es[j] += wk * sq;                               \
                    }                                                   \
                }                                                       \
            }                                                           \
            if (lane < VW) {                                            \
                _Pragma("unroll")                                       \
                for (int j = 0; j < 4; ++j) {                           \
                    vbuf2[0][lane][j0 + j] = mu[j];                     \
                    vbuf2[1][lane][j0 + j] = es[j];                     \
                }                                                       \
            }                                                           \
        }                                                               \
        /* phase 1 half B: rows j0+4..j0+7 (inputs 4..17) */            \
        {                                                               \
            f32x2 mu[4], es[4];                                         \
            _Pragma("unroll")                                           \
            for (int j = 0; j < 4; ++j) {                               \
                mu[j] = (f32x2){0.f, 0.f};                              \
                es[j] = (f32x2){0.f, 0.f};                              \
            }                                                           \
            _Pragma("unroll")                                           \
            for (int ri = 4; ri < NR; ++ri) {                           \
                f32x2 sv = {aX[ri] + bX[ri], aX[ri] - bX[ri]};          \
                f32x2 sq = sv * sv;                                     \
                _Pragma("unroll")                                       \
                for (int j = 0; j < 4; ++j) {                           \
                    int k = ri - (j + 4);                               \
                    if (k >= 0 && k < KS) {                             \
                        float wk = GW(k);                               \
                        mu[j] += wk * sv;                               \
                        es[j] += wk * sq;                               \
                    }                                                   \
                }                                                       \
            }                                                           \
            if (lane < VW) {                                            \
                _Pragma("unroll")                                       \
                for (int j = 0; j < 4; ++j) {                           \
                    vbuf2[0][lane][j0 + 4 + j] = mu[j];                 \
                    vbuf2[1][lane][j0 + 4 + j] = es[j];                 \
                }                                                       \
            }                                                           \
        }                                                               \
        const int oyc = oyX, oxc = oxX;                                 \
        /* buffer X now free: issue item I+2 into it (depth-2) */       \
        if ((I) + 2 < cnt) {                                            \
            ISSUE_INTO(aX, bX);                                         \
            oxX = rfli(ox); oyX = rfli(oy);                             \
            ADV();                                                      \
        }                                                               \
        asm volatile("s_waitcnt lgkmcnt(0)" ::: "memory");              \
        /* phase 2: horizontal conv + SSIM on OWN row */                \
        {                                                               \
            f32x2 am[2][CPT];                                           \
            _Pragma("unroll")                                           \
            for (int ch = 0; ch < 2; ++ch)                              \
                _Pragma("unroll")                                       \
                for (int j = 0; j < CPT; ++j) am[ch][j] = (f32x2){0.f, 0.f}; \
            _Pragma("unroll")                                           \
            for (int ch = 0; ch < 2; ++ch) {                            \
                _Pragma("unroll")                                       \
                for (int t = 0; t < NPOS; ++t) {                        \
                    f32x2 v = vbuf2[ch][c0 + t][rowl];                  \
                    _Pragma("unroll")                                   \
                    for (int j = 0; j < CPT; ++j) {                     \
                        int k = t - j;                                  \
                        if (k >= 0 && k < KS)                           \
                            am[ch][j] += GW(k) * v;                     \
                    }                                                   \
                }                                                       \
            }                                                           \
            const int orow = oyc + rowl;                                \
            if (orow < HO) {                                            \
                _Pragma("unroll")                                       \
                for (int j = 0; j < CPT; ++j) {                         \
                    int ocol = oxc + c0 + j;                            \
                    if (ocol < WO) {                                    \
                        f32x2 m = am[0][j], e = am[1][j];               \
                        f32x2 sq = m * m;                               \
                        float A   = 0.5f * (sq.x - sq.y);               \
                        float Bm  = 0.5f * (sq.x + sq.y);               \
                        float S12 = 0.5f * (e.x - e.y) - A;             \
                        float SS  = 0.5f * (e.x + e.y) - Bm;            \
                        float num = (A + c1) * (S12 + c2);              \
                        float den = (Bm + c1) * (SS + c2);              \
                        lsum += num * __builtin_amdgcn_rcpf(den);       \
                    }                                                   \
                }                                                       \
            }                                                           \
        }                                                               \
    }

    int i = 0;
    while (i + 1 < cnt) {
        BODY(aA, bA, oxA, oyA, i); ++i;
        BODY(aB, bB, oxB, oyB, i); ++i;
    }
    if (i < cnt) { BODY(aA, bA, oxA, oyA, i); }

    // ---------- reduction (single barrier, once per block) ----------
    #pragma unroll
    for (int off = 32; off; off >>= 1)
        lsum += __shfl_down(lsum, off, 64);
    if ((tid & 63) == 0) wsum[wv] = lsum;
    __syncthreads();
    if (tid == 0) {
        double tt = (double)wsum[0] + (double)wsum[1] +
                    (double)wsum[2] + (double)wsum[3];
        atomicAdd(acc, tt);
    }
}

__global__ void ssim_finalize(const double* __restrict__ acc,
                              float* __restrict__ out)
{
    out[0] = (float)(acc[0] / (double)(16LL * 3LL * (long long)HO * (long long)WO));
}

extern "C" void kernel_launch(void* const* d_in, const int* in_sizes, int n_in,
                              void* d_out, int out_size, void* d_ws, size_t ws_size,
                              hipStream_t stream) {
    const float* img1 = (const float*)d_in[0];
    const float* img2 = (const float*)d_in[1];
    const float* win  = (const float*)d_in[2];  // (3,1,11,11); channels identical
    float* out = (float*)d_out;
    double* acc = (double*)d_ws;

    hipMemsetAsync(acc, 0, sizeof(double), stream);

    ssim_sep_kernel<<<dim3(NBLK), 256, 0, stream>>>(img1, img2, win, acc);
    ssim_finalize<<<1, 1, 0, stream>>>(acc, out);
}

// Round 23
// 56.034 us; speedup vs baseline: 1.1149x; 1.1149x over previous
//
#include <hip/hip_runtime.h>

#define HH 512
#define WW 512
#define HO 502
#define WO 502
#define KS 11
#define OTH 32                 // v-rows per tile
#define RPT 8                  // v-rows per wave (4 waves)
#define NR  (RPT + KS - 1)     // 18 input rows per thread
#define OTW 48                 // output cols per tile (R17 geometry, proven 58.1us)
#define VW  58                 // v-cols = OTW + KS - 1
#define CSTR 33                // per-column stride in f32x2 (odd -> uniform banks)
#define CPT 6                  // output cols per thread in phase 2 (8 groups x 6)
#define NPOS (CPT + KS - 1)    // 16 tap positions

#define NTX 11                 // x tiles (11*48 = 528 >= 502)
#define NTY 16                 // y tiles
#define NTILES (NTX * NTY)     // 176
#define NZ 48                  // B*C planes
#define TOTW (NTILES * NZ)     // 8448 tile-slices
#define NBLK 1280              // 5 blocks/CU x 256 CU
#define WQ (TOTW / NBLK)       // 6
#define WR (TOTW % NBLK)       // 768 blocks take one extra

typedef float f32x2 __attribute__((ext_vector_type(2)));

__device__ __forceinline__ float rfl(float x) {
    union { float f; int i; } u;
    u.f = x;
    u.i = __builtin_amdgcn_readfirstlane(u.i);
    return u.f;
}
__device__ __forceinline__ int rfli(int x) {
    return __builtin_amdgcn_readfirstlane(x);
}

// symmetric gaussian lookup, k compile-time
#define GW(k) g[(k) < 6 ? (k) : 10 - (k)]

__global__ __launch_bounds__(256)
void ssim_sep_kernel(
    const float* __restrict__ img1, const float* __restrict__ img2,
    const float* __restrict__ win, double* __restrict__ acc)
{
    // channel-paired intermediate: chp0 = {mu_s, mu_d}, chp1 = {E[s^2], E[d^2]}
    // Wave w exclusively owns v-rows [8w, 8w+8) -> no cross-wave deps, no barriers.
    __shared__ __align__(16) f32x2 vbuf2[2][VW][CSTR];   // 30,624 B -> 5 blocks/CU
    __shared__ float wsum[4];

    const int tid = threadIdx.x;
    const int bid = blockIdx.x;

    // 1-D gaussian (wave-uniform -> SGPRs): g[k] = w[5][k]/sqrt(w[5][5]); symmetric
    float g[6];
    {
        double inv = 1.0 / sqrt((double)win[5 * KS + 5]);
        #pragma unroll
        for (int k = 0; k < 6; ++k)
            g[k] = rfl((float)((double)win[5 * KS + k] * inv));
    }

    // ---- fixed per-thread roles ----
    const int lane = tid & 63;              // phase-1 v column
    const int wv   = tid >> 6;              // wave id 0..3
    const int j0   = rfli(wv * RPT);        // first v-row owned (wave-uniform SGPR)
    const int rl = tid & 7;                 // phase-2: row within wave group
    const int cg = (tid & 63) >> 3;         // phase-2: col group 0..7
    const int c0 = cg * CPT;                // 0,6,...,42 ; max tap col 42+15=57=VW-1
    const int rowl = j0 + rl;               // local v-row for phase 2
    const float c1 = 1e-4f, c2 = 9e-4f;     // L = 1 for [0,1) inputs

    // ---- work chunk: contiguous [w0, w0+cnt) of 8448 tile-slices ----
    int w0, cnt;
    if (bid < WR) { w0 = bid * (WQ + 1);            cnt = WQ + 1; }
    else          { w0 = WR * (WQ + 1) + (bid - WR) * WQ; cnt = WQ; }
    w0 = rfli(w0); cnt = rfli(cnt);

    // one-time decomposition; block-uniform state pinned to SGPRs.
    int z   = rfli(w0 / NTILES);
    int rem = rfli(w0 % NTILES);
    int ty  = rfli(rem / NTX);
    int tx  = rfli(rem % NTX);
    int zoff = rfli(z * (HH * WW));
    int off0 = rfli(zoff + ty * (OTH * WW) + tx * OTW);
    int oy = rfli(ty * OTH), ox = rfli(tx * OTW);

    float a[NR], b[NR];

    // clamp-free fast path (interior tiles)
#define ISSUE_FAST()                                                  \
    {                                                                 \
        const float* pa_ = img1 + off0 + (j0 * WW) + lane;            \
        const float* pb_ = img2 + off0 + (j0 * WW) + lane;            \
        _Pragma("unroll")                                             \
        for (int ri = 0; ri < NR; ++ri) {                             \
            a[ri] = pa_[ri * WW];                                     \
            b[ri] = pb_[ri * WW];                                     \
        }                                                             \
    }
    // clamped path (edge tiles: tx==NTX-1 or ty==NTY-1)
#define ISSUE_EDGE()                                                  \
    {                                                                 \
        int gc_ = ox + lane; if (gc_ > WW - 1) gc_ = WW - 1;          \
        int r0_ = oy + j0;                                            \
        _Pragma("unroll")                                             \
        for (int ri = 0; ri < NR; ++ri) {                             \
            int gr_ = r0_ + ri; if (gr_ > HH - 1) gr_ = HH - 1;       \
            int ro_ = zoff + gr_ * WW + gc_;                          \
            a[ri] = img1[ro_];                                        \
            b[ri] = img2[ro_];                                        \
        }                                                             \
    }

    if (tx == NTX - 1 || ty == NTY - 1) { ISSUE_EDGE(); } else { ISSUE_FAST(); }

    float lsum = 0.f;

    for (int i = 0; i < cnt; ++i) {
        // dense VALU region: boost priority so compute-phase waves drain first
        __builtin_amdgcn_s_setprio(1);

        // ---------- fold s=a+b, d=a-b (loads issued ~1 item ago -> retired) ----------
        f32x2 sd[NR];
        #pragma unroll
        for (int ri = 0; ri < NR; ++ri)
            sd[ri] = (f32x2){a[ri] + b[ri], a[ri] - b[ri]};

        // ---------- phase 1: vertical conv, channel-paired pk math ----------
        f32x2 mu[RPT], es[RPT];             // {mu_s,mu_d}, {E[s2],E[d2]}
        #pragma unroll
        for (int j = 0; j < RPT; ++j) {
            mu[j] = (f32x2){0.f, 0.f};
            es[j] = (f32x2){0.f, 0.f};
        }
        #pragma unroll
        for (int ri = 0; ri < NR; ++ri) {
            f32x2 sv = sd[ri];
            f32x2 sq = sv * sv;             // pk_mul {s2, d2}
            #pragma unroll
            for (int j = 0; j < RPT; ++j) {
                int k = ri - j;
                if (k >= 0 && k < KS) {     // folds at compile time
                    float wk = GW(k);
                    mu[j] += wk * sv;       // pk_fma
                    es[j] += wk * sq;       // pk_fma
                }
            }
        }

        // own rows only -> no barrier; b64 writes, conflict-free
        if (lane < VW) {
            #pragma unroll
            for (int j = 0; j < RPT; ++j) {
                vbuf2[0][lane][j0 + j] = mu[j];
                vbuf2[1][lane][j0 + j] = es[j];
            }
        }

        // memory/bookkeeping region: drop priority
        __builtin_amdgcn_s_setprio(0);

        // snapshot current-item output coords (SGPR) for phase-2 masks
        const int oyc = rfli(oy), oxc = rfli(ox);

        // advance state incrementally (all SGPR) + issue next item's loads
        if (i + 1 < cnt) {
            tx = rfli(tx + 1); off0 = rfli(off0 + OTW); ox = rfli(ox + OTW);
            if (tx == NTX) {
                tx = 0; ox = 0;
                off0 = rfli(off0 + (OTH * WW) - (NTX * OTW));
                ty = rfli(ty + 1); oy = rfli(oy + OTH);
                if (ty == NTY) {
                    ty = 0; oy = 0;
                    zoff = rfli(zoff + (HH * WW));
                    off0 = zoff;
                }
            }
            if (tx == NTX - 1 || ty == NTY - 1) { ISSUE_EDGE(); } else { ISSUE_FAST(); }
        }

        // own ds_writes retired before own ds_reads; clobber pins ordering
        asm volatile("s_waitcnt lgkmcnt(0)" ::: "memory");

        // dense VALU region 2
        __builtin_amdgcn_s_setprio(1);

        // ---------- phase 2: horizontal conv + SSIM on OWN row ----------
        {
            f32x2 am[2][CPT];
            #pragma unroll
            for (int ch = 0; ch < 2; ++ch)
                #pragma unroll
                for (int j = 0; j < CPT; ++j) am[ch][j] = (f32x2){0.f, 0.f};

            #pragma unroll
            for (int ch = 0; ch < 2; ++ch) {
                #pragma unroll
                for (int t = 0; t < NPOS; ++t) {
                    f32x2 v = vbuf2[ch][c0 + t][rowl];
                    #pragma unroll
                    for (int j = 0; j < CPT; ++j) {
                        int k = t - j;
                        if (k >= 0 && k < KS)        // folds at compile time
                            am[ch][j] += GW(k) * v;  // pk_fma
                    }
                }
            }

            const int orow = oyc + rowl;
            if (orow < HO) {
                #pragma unroll
                for (int j = 0; j < CPT; ++j) {
                    int ocol = oxc + c0 + j;
                    if (ocol < WO) {
                        f32x2 m = am[0][j], e = am[1][j];
                        f32x2 sq = m * m;                  // {mus^2, mud^2}
                        float A   = 0.5f * (sq.x - sq.y);  // 2*mu1*mu2
                        float Bm  = 0.5f * (sq.x + sq.y);  // mu1^2 + mu2^2
                        float S12 = 0.5f * (e.x - e.y) - A;   // 2*sigma12
                        float SS  = 0.5f * (e.x + e.y) - Bm;  // sig1^2 + sig2^2
                        float num = (A + c1) * (S12 + c2);
                        float den = (Bm + c1) * (SS + c2);
                        lsum += num * __builtin_amdgcn_rcpf(den);
                    }
                }
            }
        }

        __builtin_amdgcn_s_setprio(0);
    }

    // ---------- reduction (single barrier, once per block) ----------
    #pragma unroll
    for (int off = 32; off; off >>= 1)
        lsum += __shfl_down(lsum, off, 64);
    if ((tid & 63) == 0) wsum[wv] = lsum;
    __syncthreads();
    if (tid == 0) {
        double tt = (double)wsum[0] + (double)wsum[1] +
                    (double)wsum[2] + (double)wsum[3];
        atomicAdd(acc, tt);
    }
}

__global__ void ssim_finalize(const double* __restrict__ acc,
                              float* __restrict__ out)
{
    out[0] = (float)(acc[0] / (double)(16LL * 3LL * (long long)HO * (long long)WO));
}

extern "C" void kernel_launch(void* const* d_in, const int* in_sizes, int n_in,
                              void* d_out, int out_size, void* d_ws, size_t ws_size,
                              hipStream_t stream) {
    const float* img1 = (const float*)d_in[0];
    const float* img2 = (const float*)d_in[1];
    const float* win  = (const float*)d_in[2];  // (3,1,11,11); channels identical
    float* out = (float*)d_out;
    double* acc = (double*)d_ws;

    hipMemsetAsync(acc, 0, sizeof(double), stream);

    ssim_sep_kernel<<<dim3(NBLK), 256, 0, stream>>>(img1, img2, win, acc);
    ssim_finalize<<<1, 1, 0, stream>>>(acc, out);
}